// Round 5
// baseline (197.039 us; speedup 1.0000x reference)
//
#include <hip/hip_runtime.h>
#include <math.h>

#define N_NODES 50000
#define N_EDGES 800000
#define EE_TOTAL (N_EDGES + N_NODES)
#define CAP 64  // bucket capacity; in-degree ~ Binomial(800K, 1/50K), P(>64) ~ 1e-13

typedef __attribute__((ext_vector_type(8))) short bf16x8;
typedef __attribute__((ext_vector_type(4))) float f32x4;

__device__ __forceinline__ float bf2f(unsigned short s) {
  return __uint_as_float((unsigned)s << 16);
}
__device__ __forceinline__ unsigned short f2bf(float f) {
  unsigned u = __float_as_uint(f);
  return (unsigned short)((u + 0x7FFFu + ((u >> 16) & 1u)) >> 16);  // RNE
}
__device__ __forceinline__ float lrelu(float e) { return e > 0.f ? e : 0.2f * e; }

// ---------------------------------------------------------------- prep
// W1t[n][k] = bf16(W1[k][n]); W2t[n][k] = bf16(W2[k][n]); counts = 0.
__global__ void prep_kernel(const float* __restrict__ W1, const float* __restrict__ W2,
                            unsigned short* __restrict__ W1t, unsigned short* __restrict__ W2t,
                            int* __restrict__ counts) {
  int i = blockIdx.x * blockDim.x + threadIdx.x;
  if (i < N_NODES) counts[i] = 0;
  if (i < 256 * 128) W1t[i] = f2bf(W1[(i & 127) * 256 + (i >> 7)]);
  if (i < 64 * 256) W2t[i] = f2bf(W2[(i & 255) * 64 + (i >> 8)]);
}

// ---------------------------------------------------------------- bucket scatter
__global__ void scatter_kernel(const int* __restrict__ src, const int* __restrict__ dst,
                               int* __restrict__ counts, int* __restrict__ col) {
  int i = blockIdx.x * blockDim.x + threadIdx.x;
  if (i >= EE_TOTAL) return;
  int s, d;
  if (i < N_EDGES) { s = src[i]; d = dst[i]; } else { s = i - N_EDGES; d = s; }
  int pos = atomicAdd(&counts[d], 1);
  if (pos < CAP) col[(size_t)d * CAP + pos] = s;
}

// ---------------------------------------------------------------- GEMM1 (MFMA)
// h1 = x @ W1 : [50000,128] x [128,256] -> bf16 h1b [M][256]; alpha1 fused.
__global__ __launch_bounds__(256) void gemm1_kernel(const float* __restrict__ A,        // x [M][128] f32
                                                    const unsigned short* __restrict__ Bt, // [256][128]
                                                    unsigned short* __restrict__ Cb,       // [M][256]
                                                    const float* __restrict__ att_s,
                                                    const float* __restrict__ att_d,
                                                    float* __restrict__ as_out,            // [M*4]
                                                    float* __restrict__ ad_out) {
  __shared__ unsigned short Bs[256 * 128];  // 64KB, XOR-swizzled
  const int M = N_NODES;
  int t = threadIdx.x;
  int lane = t & 63, w = t >> 6;
  int row0 = blockIdx.x * 64;
#pragma unroll
  for (int i = 0; i < 16; ++i) {
    int idx = i * 256 + t;
    int n = idx >> 4;  // row = 256B = 16 chunks
    uint4 v = ((const uint4*)Bt)[idx];
    int byte = (idx * 16) ^ ((n & 7) << 4);
    *(uint4*)((char*)Bs + byte) = v;
  }
  __syncthreads();
  int rl = lane & 15, kg = lane >> 4;
  f32x4 acc[4][4] = {};
  for (int ks = 0; ks < 4; ++ks) {
    bf16x8 af[4], bfr[4];
#pragma unroll
    for (int rb = 0; rb < 4; ++rb) {
      int row = row0 + rb * 16 + rl;
      float4 v0 = make_float4(0.f, 0.f, 0.f, 0.f), v1 = v0;
      if (row < M) {
        const float* p = A + (size_t)row * 128 + ks * 32 + kg * 8;
        v0 = *(const float4*)p;
        v1 = *(const float4*)(p + 4);
      }
      bf16x8 a;
      a[0] = (short)f2bf(v0.x); a[1] = (short)f2bf(v0.y);
      a[2] = (short)f2bf(v0.z); a[3] = (short)f2bf(v0.w);
      a[4] = (short)f2bf(v1.x); a[5] = (short)f2bf(v1.y);
      a[6] = (short)f2bf(v1.z); a[7] = (short)f2bf(v1.w);
      af[rb] = a;
    }
#pragma unroll
    for (int cb = 0; cb < 4; ++cb) {
      int n = w * 64 + cb * 16 + rl;
      int byte = (n * 256 + ks * 64 + kg * 16) ^ ((n & 7) << 4);
      bfr[cb] = *(const bf16x8*)((char*)Bs + byte);
    }
#pragma unroll
    for (int rb = 0; rb < 4; ++rb)
#pragma unroll
      for (int cb = 0; cb < 4; ++cb)
        acc[rb][cb] = __builtin_amdgcn_mfma_f32_16x16x32_bf16(af[rb], bfr[cb], acc[rb][cb], 0, 0, 0);
  }
  float asv[4], adv[4];
#pragma unroll
  for (int cb = 0; cb < 4; ++cb) {
    int c = w * 64 + cb * 16 + rl;
    asv[cb] = att_s[c];
    adv[cb] = att_d[c];
  }
#pragma unroll
  for (int rb = 0; rb < 4; ++rb) {
#pragma unroll
    for (int r = 0; r < 4; ++r) {
      int row = row0 + rb * 16 + kg * 4 + r;
      bool ok = row < M;
      float sp = 0.f, dp = 0.f;
#pragma unroll
      for (int cb = 0; cb < 4; ++cb) {
        float v = acc[rb][cb][r];
        if (ok) Cb[(size_t)row * 256 + w * 64 + cb * 16 + rl] = f2bf(v);
        sp += v * asv[cb];
        dp += v * adv[cb];
      }
#pragma unroll
      for (int off = 1; off < 16; off <<= 1) {
        sp += __shfl_xor(sp, off, 64);
        dp += __shfl_xor(dp, off, 64);
      }
      if (ok && rl == 0) {
        as_out[row * 4 + w] = sp;
        ad_out[row * 4 + w] = dp;
      }
    }
  }
}

// ---------------------------------------------------------------- GEMM2 (MFMA)
// h2 = x2b @ W2 : [50000,256] x [256,64] -> bf16 h2b [M][64]; alpha2 fused.
__global__ __launch_bounds__(256) void gemm2_kernel(const unsigned short* __restrict__ A,   // x2b [M][256]
                                                    const unsigned short* __restrict__ Bt,  // [64][256]
                                                    unsigned short* __restrict__ Cb,        // [M][64]
                                                    const float* __restrict__ att_s,
                                                    const float* __restrict__ att_d,
                                                    float* __restrict__ as_out,             // [M]
                                                    float* __restrict__ ad_out) {
  __shared__ unsigned short Bs[64 * 256];  // 32KB
  const int M = N_NODES;
  int t = threadIdx.x;
  int lane = t & 63, w = t >> 6;
  int row0 = blockIdx.x * 64;
#pragma unroll
  for (int i = 0; i < 8; ++i) {
    int idx = i * 256 + t;
    int n = idx >> 5;  // row = 512B = 32 chunks
    uint4 v = ((const uint4*)Bt)[idx];
    int byte = (idx * 16) ^ ((n & 7) << 4);
    *(uint4*)((char*)Bs + byte) = v;
  }
  __syncthreads();
  int rl = lane & 15, kg = lane >> 4;
  int arow = row0 + w * 16 + rl;
  f32x4 acc[4] = {};
  for (int ks = 0; ks < 8; ++ks) {
    bf16x8 a = {};
    if (arow < M) a = *(const bf16x8*)(A + (size_t)arow * 256 + ks * 32 + kg * 8);
#pragma unroll
    for (int cb = 0; cb < 4; ++cb) {
      int n = cb * 16 + rl;
      int byte = (n * 512 + ks * 64 + kg * 16) ^ ((n & 7) << 4);
      bf16x8 b = *(const bf16x8*)((char*)Bs + byte);
      acc[cb] = __builtin_amdgcn_mfma_f32_16x16x32_bf16(a, b, acc[cb], 0, 0, 0);
    }
  }
  float asv[4], adv[4];
#pragma unroll
  for (int cb = 0; cb < 4; ++cb) {
    int c = cb * 16 + rl;
    asv[cb] = att_s[c];
    adv[cb] = att_d[c];
  }
#pragma unroll
  for (int r = 0; r < 4; ++r) {
    int orow = row0 + w * 16 + kg * 4 + r;
    bool ok = orow < M;
    float sp = 0.f, dp = 0.f;
#pragma unroll
    for (int cb = 0; cb < 4; ++cb) {
      float v = acc[cb][r];
      if (ok) Cb[(size_t)orow * 64 + cb * 16 + rl] = f2bf(v);
      sp += v * asv[cb];
      dp += v * adv[cb];
    }
#pragma unroll
    for (int off = 1; off < 16; off <<= 1) {
      sp += __shfl_xor(sp, off, 64);
      dp += __shfl_xor(dp, off, 64);
    }
    if (ok && rl == 0) {
      as_out[orow] = sp;
      ad_out[orow] = dp;
    }
  }
}

// ---------------------------------------------------------------- layer 1 agg
// one wave per dst node. Phase 1: 64 lanes compute p for up to 64 edges (pad
// with p=0 self-edges to a multiple of 4). Phase 2: 4 edges/iter, lane = (edge
// e=lane>>4, channel-group cg=lane&15), 32B/lane via 2x bf16x8, 2-deep pipeline
// -> 4 outstanding loads/lane.
__global__ __launch_bounds__(256) void agg1_kernel(const unsigned short* __restrict__ h1b,
                                                   const float* __restrict__ as,
                                                   const float* __restrict__ ad,
                                                   const int* __restrict__ counts,
                                                   const int* __restrict__ col,
                                                   const float* __restrict__ b1,
                                                   unsigned short* __restrict__ x2b) {
  __shared__ int s_lds[4][64];
  __shared__ float p_lds[4][64][4];  // [wave][edge][head]
  int t = threadIdx.x;
  int lane = t & 63, w = t >> 6;
  int node = blockIdx.x * 4 + w;
  if (node >= N_NODES) return;
  int cnt = min(counts[node], CAP);
  const int* cbase = col + (size_t)node * CAP;
  float4 adn = *(const float4*)(ad + node * 4);
  // phase 1
  float4 p = make_float4(0.f, 0.f, 0.f, 0.f);
  int s = node;
  if (lane < cnt) {
    s = cbase[lane];
    float4 a4 = *(const float4*)(as + s * 4);
    p.x = __expf(lrelu(a4.x + adn.x));
    p.y = __expf(lrelu(a4.y + adn.y));
    p.z = __expf(lrelu(a4.z + adn.z));
    p.w = __expf(lrelu(a4.w + adn.w));
  }
  s_lds[w][lane] = s;
  *(float4*)&p_lds[w][lane][0] = p;
  float4 den = p;
#pragma unroll
  for (int off = 1; off < 64; off <<= 1) {
    den.x += __shfl_xor(den.x, off, 64);
    den.y += __shfl_xor(den.y, off, 64);
    den.z += __shfl_xor(den.z, off, 64);
    den.w += __shfl_xor(den.w, off, 64);
  }
  // phase 2
  int e = lane >> 4, cg = lane & 15, chb = cg * 16, hd = cg >> 2;
  float acc[16] = {};
  int nq = (cnt + 3) & ~3;  // cnt >= 1 (self-loop) -> nq >= 4
  int s_c = s_lds[w][e];
  float p_c = p_lds[w][e][hd];
  const unsigned short* pb = h1b + (size_t)s_c * 256 + chb;
  bf16x8 va = *(const bf16x8*)pb;
  bf16x8 vb = *(const bf16x8*)(pb + 8);
  for (int j = 4; j < nq; j += 4) {
    int s_n = s_lds[w][j + e];
    float p_n = p_lds[w][j + e][hd];
    const unsigned short* pn = h1b + (size_t)s_n * 256 + chb;
    bf16x8 wa = *(const bf16x8*)pn;
    bf16x8 wb = *(const bf16x8*)(pn + 8);
#pragma unroll
    for (int k = 0; k < 8; ++k) {
      acc[k] += p_c * bf2f((unsigned short)va[k]);
      acc[8 + k] += p_c * bf2f((unsigned short)vb[k]);
    }
    va = wa; vb = wb; p_c = p_n;
  }
#pragma unroll
  for (int k = 0; k < 8; ++k) {
    acc[k] += p_c * bf2f((unsigned short)va[k]);
    acc[8 + k] += p_c * bf2f((unsigned short)vb[k]);
  }
  // reduce across the 4 lanes sharing each channel group (xor 16, 32)
#pragma unroll
  for (int k = 0; k < 16; ++k) {
    acc[k] += __shfl_xor(acc[k], 16, 64);
    acc[k] += __shfl_xor(acc[k], 32, 64);
  }
  if (e == 0) {
    float dh = (hd == 0) ? den.x : (hd == 1) ? den.y : (hd == 2) ? den.z : den.w;
    float inv = 1.f / (dh + 1e-16f);
    float bb[16];
#pragma unroll
    for (int q = 0; q < 4; ++q) *(float4*)&bb[q * 4] = *(const float4*)(b1 + chb + q * 4);
    bf16x8 o1, o2;
#pragma unroll
    for (int k = 0; k < 8; ++k) {
      o1[k] = (short)f2bf(fmaxf(acc[k] * inv + bb[k], 0.f));
      o2[k] = (short)f2bf(fmaxf(acc[8 + k] * inv + bb[8 + k], 0.f));
    }
    *(bf16x8*)(x2b + (size_t)node * 256 + chb) = o1;
    *(bf16x8*)(x2b + (size_t)node * 256 + chb + 8) = o2;
  }
}

// ---------------------------------------------------------------- layer 2 agg + head
// one wave per dst node; 8 edges/iter (e=lane>>3, cg=lane&7), 16B/lane,
// 2-deep pipeline -> 2 outstanding loads/lane.
__global__ __launch_bounds__(256) void agg2_final_kernel(const unsigned short* __restrict__ h2b,
                                                         const float* __restrict__ as,
                                                         const float* __restrict__ ad,
                                                         const int* __restrict__ counts,
                                                         const int* __restrict__ col,
                                                         const float* __restrict__ b2,
                                                         const float* __restrict__ Wout,
                                                         const float* __restrict__ bout,
                                                         float* __restrict__ out) {
  __shared__ int s_lds[4][64];
  __shared__ float p_lds[4][64];
  int t = threadIdx.x;
  int lane = t & 63, w = t >> 6;
  int node = blockIdx.x * 4 + w;
  if (node >= N_NODES) return;
  int cnt = min(counts[node], CAP);
  const int* cbase = col + (size_t)node * CAP;
  float adn = ad[node];
  float p = 0.f;
  int s = node;
  if (lane < cnt) {
    s = cbase[lane];
    p = __expf(lrelu(as[s] + adn));
  }
  s_lds[w][lane] = s;
  p_lds[w][lane] = p;
  float den = p;
#pragma unroll
  for (int off = 1; off < 64; off <<= 1) den += __shfl_xor(den, off, 64);
  int e = lane >> 3, cg = lane & 7, chb = cg * 8;
  float acc[8] = {};
  int nq = (cnt + 7) & ~7;  // >= 8
  int s_c = s_lds[w][e];
  float p_c = p_lds[w][e];
  bf16x8 va = *(const bf16x8*)(h2b + (size_t)s_c * 64 + chb);
  for (int j = 8; j < nq; j += 8) {
    int s_n = s_lds[w][j + e];
    float p_n = p_lds[w][j + e];
    bf16x8 wa = *(const bf16x8*)(h2b + (size_t)s_n * 64 + chb);
#pragma unroll
    for (int k = 0; k < 8; ++k) acc[k] += p_c * bf2f((unsigned short)va[k]);
    va = wa; p_c = p_n;
  }
#pragma unroll
  for (int k = 0; k < 8; ++k) acc[k] += p_c * bf2f((unsigned short)va[k]);
  // reduce across 8 lanes sharing each channel group (xor 8, 16, 32)
#pragma unroll
  for (int k = 0; k < 8; ++k) {
    acc[k] += __shfl_xor(acc[k], 8, 64);
    acc[k] += __shfl_xor(acc[k], 16, 64);
    acc[k] += __shfl_xor(acc[k], 32, 64);
  }
  float part = 0.f;
  if (e == 0) {
    float inv = 1.f / (den + 1e-16f);
    float bb[8], ww[8];
    *(float4*)&bb[0] = *(const float4*)(b2 + chb);
    *(float4*)&bb[4] = *(const float4*)(b2 + chb + 4);
    *(float4*)&ww[0] = *(const float4*)(Wout + chb);
    *(float4*)&ww[4] = *(const float4*)(Wout + chb + 4);
#pragma unroll
    for (int k = 0; k < 8; ++k) part += fmaxf(acc[k] * inv + bb[k], 0.f) * ww[k];
  }
#pragma unroll
  for (int off = 1; off < 8; off <<= 1) part += __shfl_xor(part, off, 64);
  if (lane == 0) out[node] = part + bout[0];
}

// ---------------------------------------------------------------- launch
extern "C" void kernel_launch(void* const* d_in, const int* in_sizes, int n_in,
                              void* d_out, int out_size, void* d_ws, size_t ws_size,
                              hipStream_t stream) {
  const float* x    = (const float*)d_in[0];
  const int*   ei   = (const int*)d_in[1];
  const float* W1   = (const float*)d_in[2];
  const float* as1w = (const float*)d_in[3];
  const float* ad1w = (const float*)d_in[4];
  const float* b1   = (const float*)d_in[5];
  const float* W2   = (const float*)d_in[6];
  const float* as2w = (const float*)d_in[7];
  const float* ad2w = (const float*)d_in[8];
  const float* b2   = (const float*)d_in[9];
  const float* Wout = (const float*)d_in[10];
  const float* bout = (const float*)d_in[11];
  float* out = (float*)d_out;

  const int* src = ei;
  const int* dst = ei + N_EDGES;

  char* ws = (char*)d_ws;
  size_t off = 0;
  auto alloc = [&](size_t bytes) -> char* {
    char* p = ws + off;
    off += (bytes + 255) & ~(size_t)255;
    return p;
  };
  int*            counts = (int*)alloc((size_t)N_NODES * 4);
  int*            col    = (int*)alloc((size_t)N_NODES * CAP * 4);
  unsigned short* W1t    = (unsigned short*)alloc((size_t)256 * 128 * 2);
  unsigned short* W2t    = (unsigned short*)alloc((size_t)64 * 256 * 2);
  unsigned short* x2b    = (unsigned short*)alloc((size_t)N_NODES * 256 * 2);
  unsigned short* hbuf   = (unsigned short*)alloc((size_t)N_NODES * 256 * 2);
  float*          as1    = (float*)alloc((size_t)N_NODES * 4 * 4);
  float*          ad1    = (float*)alloc((size_t)N_NODES * 4 * 4);
  float*          as2    = (float*)alloc((size_t)N_NODES * 4);
  float*          ad2    = (float*)alloc((size_t)N_NODES * 4);

  unsigned short* h1b = hbuf;  // [M][256] bf16, dead after agg1
  unsigned short* h2b = hbuf;  // [M][64]  bf16, written by gemm2 (after agg1)

  const int edge_blocks = (EE_TOTAL + 255) / 256;
  const int node_blocks4 = (N_NODES + 3) / 4;
  const int gemm_blocks = (N_NODES + 63) / 64;

  prep_kernel<<<(N_NODES + 255) / 256, 256, 0, stream>>>(W1, W2, W1t, W2t, counts);
  scatter_kernel<<<edge_blocks, 256, 0, stream>>>(src, dst, counts, col);

  // layer 1
  gemm1_kernel<<<gemm_blocks, 256, 0, stream>>>(x, W1t, h1b, as1w, ad1w, as1, ad1);
  agg1_kernel<<<node_blocks4, 256, 0, stream>>>(h1b, as1, ad1, counts, col, b1, x2b);

  // layer 2
  gemm2_kernel<<<gemm_blocks, 256, 0, stream>>>(x2b, W2t, h2b, as2w, ad2w, as2, ad2);
  agg2_final_kernel<<<node_blocks4, 256, 0, stream>>>(h2b, as2, ad2, counts, col, b2,
                                                      Wout, bout, out);
}